// Round 12
// baseline (319.640 us; speedup 1.0000x reference)
//
#include <hip/hip_runtime.h>
#include <cstdint>
#include <cstddef>

// Problem constants
//   x[1024,256] f32, W1[1024,256] f32, b1[1024], W2[32896,1024] f32, b2[32896]
//   h = softplus(x@W1^T + b1)          [1024,1024]  (bf16 in ws)
//   elements = h@W2^T + b2             first TRI=32640 cols used
//   out[b,i,j] = elements[b, i(i-1)/2+j] for i>j; out[b,j,i] = -that; diag 0
#define TRI 32640

using u32   = unsigned int;
using u16   = unsigned short;
using f32x4 = __attribute__((ext_vector_type(4))) float;
using u32x4 = __attribute__((ext_vector_type(4))) u32;
using bf16x8 = __attribute__((ext_vector_type(8))) short;

__device__ __forceinline__ void gload_lds16(const void* g, void* l) {
  // async global->LDS, 16B/lane; LDS dest = wave-uniform base + lane*16
  __builtin_amdgcn_global_load_lds(
      (const __attribute__((address_space(1))) void*)g,
      (__attribute__((address_space(3))) void*)l, 16, 0, 0);
}

__device__ __forceinline__ u32 pack2bf(float a, float b) {  // truncating
  u32 ua = __builtin_bit_cast(u32, a);
  u32 ub = __builtin_bit_cast(u32, b);
  return (ub & 0xffff0000u) | (ua >> 16);
}

__device__ __forceinline__ u16 f2bf_rn(float f) {  // round-to-nearest-even
  u32 u = __builtin_bit_cast(u32, f);
  u += 0x7fffu + ((u >> 16) & 1u);
  return (u16)(u >> 16);
}

#define MEMFENCE asm volatile("" ::: "memory")

// ---------------------------------------------------------------------------
// K1: h = softplus(x @ W1^T + b1), bf16 plain layout. 64 blocks (r1-proven).
// No W2 conversion pass anymore — k2 reads W2 f32 directly.
// ---------------------------------------------------------------------------
__global__ __launch_bounds__(256)
void k1_gemm_softplus(const float* __restrict__ x, const float* __restrict__ W1,
                      const float* __restrict__ b1, u16* __restrict__ h)
{
  __shared__ float ldsA[128*32];
  __shared__ float ldsB[128*32];
  const int tid = threadIdx.x, lane = tid & 63, wave = tid >> 6;
  const int wm = wave >> 1, wn = wave & 1;
  const int brow = (blockIdx.x & 7) * 128, bcol = (blockIdx.x >> 3) * 128;
  const int s_row = wave*8 + (lane >> 3);
  const int s_col = (lane & 7) * 4;
  const float* gA = x  + (brow + s_row)*256 + s_col;
  const float* gB = W1 + (bcol + s_row)*256 + s_col;
  float* lA = &ldsA[wave*256];
  float* lB = &ldsB[wave*256];
  const int fr = lane & 15, fk = (lane >> 4) * 8;
  const float* rdA = &ldsA[(wm*64 + fr)*32 + fk];
  const float* rdB = &ldsB[(wn*64 + fr)*32 + fk];
  f32x4 acc[4][4] = {};
  for (int kt = 0; kt < 8; ++kt) {
    __syncthreads();
#pragma unroll
    for (int q = 0; q < 4; ++q) {
      gload_lds16(gA + q*32*256 + kt*32, lA + q*1024);
      gload_lds16(gB + q*32*256 + kt*32, lB + q*1024);
    }
    __syncthreads();
    bf16x8 af[4], bfv[4];
#pragma unroll
    for (int m = 0; m < 4; ++m) {
      f32x4 lo = *(const f32x4*)(rdA + m*512);
      f32x4 hi = *(const f32x4*)(rdA + m*512 + 4);
      u32x4 p = { pack2bf(lo.x,lo.y), pack2bf(lo.z,lo.w),
                  pack2bf(hi.x,hi.y), pack2bf(hi.z,hi.w) };
      af[m] = __builtin_bit_cast(bf16x8, p);
    }
#pragma unroll
    for (int n = 0; n < 4; ++n) {
      f32x4 lo = *(const f32x4*)(rdB + n*512);
      f32x4 hi = *(const f32x4*)(rdB + n*512 + 4);
      u32x4 p = { pack2bf(lo.x,lo.y), pack2bf(lo.z,lo.w),
                  pack2bf(hi.x,hi.y), pack2bf(hi.z,hi.w) };
      bfv[n] = __builtin_bit_cast(bf16x8, p);
    }
#pragma unroll
    for (int m = 0; m < 4; ++m)
#pragma unroll
      for (int n = 0; n < 4; ++n)
        acc[m][n] = __builtin_amdgcn_mfma_f32_16x16x32_bf16(af[m], bfv[n], acc[m][n], 0,0,0);
  }
#pragma unroll
  for (int n = 0; n < 4; ++n) {
    const int col = bcol + wn*64 + n*16 + fr;
    const float bias = b1[col];
#pragma unroll
    for (int m = 0; m < 4; ++m) {
      const int row0 = brow + wm*64 + m*16 + (lane >> 4)*4;
#pragma unroll
      for (int r = 0; r < 4; ++r) {
        float z = acc[m][n][r] + bias;
        float sp = fmaxf(z, 0.f) + log1pf(expf(-fabsf(z)));
        h[(row0 + r)*1024 + col] = f2bf_rn(sp);
      }
    }
  }
}

// ---------------------------------------------------------------------------
// K2: elements = h @ W2^T (+b2), forward-half scatter. B READ AS F32 DIRECTLY
// (no conversion pass): staged f32 into LDS via the 3-slot counted pipeline,
// packed to bf16 at fragment-read (truncation — r1-proven, absmax 0.094).
// 128x128 tile, BK=32, 4 waves (2Mx2N), 72 KB LDS (3 slots x [A 8K | B f32
// 16K]) -> 2 blocks/CU. Unpinned schedule (r11). Counted vmcnt(6)/tile.
//
// B LDS layout: [128 rows][32 K] f32, 128B rows = 8x16B units.
//   swizzle: unit ^= (row & 7)  -> 16 lanes per unit-col hit 8 distinct
//   slots (2-way alias = free). Both-sides: staging source unit inverse-
//   permuted, read slot = wanted_unit ^ (row&7).
// A unchanged (bf16, 64B rows, unit ^= (row>>1)&3, r3-proven).
// Grid 2040 = 8 brow x 255 ttile (t-tile 255 would be all t>=TRI: dropped).
// ---------------------------------------------------------------------------
#define SLOT 24576u    // 8KB A + 16KB B per slot

__global__ __launch_bounds__(256)
void k2_gemm_f32b(const u16* __restrict__ h, const float* __restrict__ W2,
                  const float* __restrict__ b2, float* __restrict__ out)
{
  __shared__ char lds[73728];     // 72 KB: slot s @ s*24576; A @+0, B @+8192

  const int tid = threadIdx.x, lane = tid & 63, wv = tid >> 6;   // wv 0..3
  const int wm = wv >> 1, wn = wv & 1;                           // 2M x 2N

  // XCD swizzle (2040 % 8 == 0), r1-proven index math:
  const int L = (blockIdx.x & 7) * 255 + (blockIdx.x >> 3);
  const int brow = (L & 7) * 128;          // batch tile
  const int t0   = (L >> 3) * 128;         // t tile (0..32512)

  // ---- A staging (r10-proven): 2 issues/wave, 16 rows each ----
  const int srowA = wv*16 + (lane >> 2);
  const int suA   = (lane & 3) ^ ((lane >> 3) & 3);
  const u16* sA0 = h + (size_t)(brow + srowA     )*1024 + suA*8;
  const u16* sA1 = h + (size_t)(brow + srowA + 64)*1024 + suA*8;
  const u32 dA0 = (u32)wv*1024u, dA1 = dA0 + 4096u;

  // ---- B staging (f32): 4 issues/wave, 8 rows each (1KB = 8 x 128B) ----
  const int srowB = lane >> 3;                      // 0..7
  const int suB   = (lane & 7) ^ (lane >> 3);       // ^ (row&7)
  const float* sB0 = W2 + (size_t)(t0 + wv*8 +  0 + srowB)*1024 + suB*4;
  const float* sB1 = W2 + (size_t)(t0 + wv*8 + 32 + srowB)*1024 + suB*4;
  const float* sB2 = W2 + (size_t)(t0 + wv*8 + 64 + srowB)*1024 + suB*4;
  const float* sB3 = W2 + (size_t)(t0 + wv*8 + 96 + srowB)*1024 + suB*4;
  const u32 dB0 = 8192u + (u32)wv*1024u;
  const u32 dB1 = dB0 + 4096u, dB2 = dB0 + 8192u, dB3 = dB0 + 12288u;

  // ---- ds_read offsets ----
  const int fr = lane & 15, lg = lane >> 4;
  const u32 auoff = (u32)((lg ^ ((fr >> 1) & 3)) * 16);
  u32 aoff[4], boffL[4], boffH[4];
#pragma unroll
  for (int m = 0; m < 4; ++m)
    aoff[m] = (u32)((wm*64 + m*16 + fr) * 64) + auoff;
  const int bk = fr & 7;
#pragma unroll
  for (int n = 0; n < 4; ++n) {
    const u32 base = 8192u + (u32)((wn*64 + n*16 + fr) * 128);
    boffL[n] = base + (u32)(((2*lg    ) ^ bk) * 16);   // f32 k = lg*8+0..3
    boffH[n] = base + (u32)(((2*lg + 1) ^ bk) * 16);   // f32 k = lg*8+4..7
  }

  f32x4 acc[4][4] = {};

#define STAGE(kt, sb)                                                         \
  {                                                                           \
    gload_lds16(sA0 + (kt)*32, lds + (sb) + dA0);                             \
    gload_lds16(sA1 + (kt)*32, lds + (sb) + dA1);                             \
    gload_lds16(sB0 + (kt)*32, lds + (sb) + dB0);                             \
    gload_lds16(sB1 + (kt)*32, lds + (sb) + dB1);                             \
    gload_lds16(sB2 + (kt)*32, lds + (sb) + dB2);                             \
    gload_lds16(sB3 + (kt)*32, lds + (sb) + dB3);                             \
  }

  // ---- prologue: stage tiles 0,1; wait tile 0 (keep tile 1's 6) ----
  STAGE(0, 0u)
  STAGE(1, SLOT)
  asm volatile("s_waitcnt vmcnt(6)" ::: "memory");
  MEMFENCE; __builtin_amdgcn_s_barrier(); MEMFENCE;

  u32 rb = 0u, wb = 2u*SLOT;      // read slot t%3, write slot (t+2)%3
#pragma unroll 2
  for (int t = 0; t < 32; ++t) {
    const int kb = ((t+2 < 32) ? t+2 : 31) * 32;   // clamped; dup benign

    bf16x8 a0 = *(const bf16x8*)(lds + rb + aoff[0]);
    bf16x8 a1 = *(const bf16x8*)(lds + rb + aoff[1]);
    bf16x8 a2 = *(const bf16x8*)(lds + rb + aoff[2]);
    bf16x8 a3 = *(const bf16x8*)(lds + rb + aoff[3]);
    bf16x8 bfv[4];
#pragma unroll
    for (int n = 0; n < 4; ++n) {
      f32x4 lo = *(const f32x4*)(lds + rb + boffL[n]);
      f32x4 hi = *(const f32x4*)(lds + rb + boffH[n]);
      u32x4 p = { pack2bf(lo.x,lo.y), pack2bf(lo.z,lo.w),
                  pack2bf(hi.x,hi.y), pack2bf(hi.z,hi.w) };
      bfv[n] = __builtin_bit_cast(bf16x8, p);
    }

    // stage tile t+2 into slot (t+2)%3 (holds t-1, consumed last iter)
    STAGE(kb >> 5 == 0 ? 0 : (kb / 32), wb)   // kb is element offset /32 = kt

#pragma unroll
    for (int m = 0; m < 4; ++m) {
      const bf16x8 am = (m==0)?a0:(m==1)?a1:(m==2)?a2:a3;
      acc[m][0] = __builtin_amdgcn_mfma_f32_16x16x32_bf16(am, bfv[0], acc[m][0], 0,0,0);
      acc[m][1] = __builtin_amdgcn_mfma_f32_16x16x32_bf16(am, bfv[1], acc[m][1], 0,0,0);
      acc[m][2] = __builtin_amdgcn_mfma_f32_16x16x32_bf16(am, bfv[2], acc[m][2], 0,0,0);
      acc[m][3] = __builtin_amdgcn_mfma_f32_16x16x32_bf16(am, bfv[3], acc[m][3], 0,0,0);
    }

    // tile t+1 (oldest 6 outstanding) must be in LDS before anyone reads it
    asm volatile("s_waitcnt vmcnt(6)" ::: "memory");
    MEMFENCE; __builtin_amdgcn_s_barrier(); MEMFENCE;

    rb = (rb == 2u*SLOT) ? 0u : rb + SLOT;
    wb = (wb == 2u*SLOT) ? 0u : wb + SLOT;
  }
#undef STAGE
  asm volatile("s_waitcnt vmcnt(0)" ::: "memory");   // drain tail dup DMAs

  // ---- epilogue: t -> (i,j) strict-lower scatter, forward half only ----
#pragma unroll
  for (int n = 0; n < 4; ++n) {
    const int t = t0 + wn*64 + n*16 + fr;
    if (t >= TRI) continue;
    const float bias = b2[t];
    int i = (int)((1.0f + sqrtf((float)(8*t + 1))) * 0.5f);
    while (i*(i+1)/2 <= t) ++i;
    while (i*(i-1)/2 > t) --i;
    const int j = t - i*(i-1)/2;
    const int ijbase = i*256 + j;
#pragma unroll
    for (int m = 0; m < 4; ++m) {
      const int row0 = brow + wm*64 + m*16 + lg*4;
#pragma unroll
      for (int r = 0; r < 4; ++r)
        out[(size_t)(row0 + r)*65536 + ijbase] = acc[m][n][r] + bias;
    }
  }
}

// ---------------------------------------------------------------------------
// K3: antisymmetrize. Read lower 64x64 tiles, write -tile^T to upper.
// ---------------------------------------------------------------------------
__global__ __launch_bounds__(256)
void k3_mirror(float* __restrict__ out)
{
  __shared__ float tile[64][65];
  const int b = blockIdx.y;
  const int k = blockIdx.x;
  int ib, jb;
  if (k < 4) { ib = k; jb = k; }
  else {
    const int pi[6] = {1,2,2,3,3,3};
    const int pj[6] = {0,0,1,0,1,2};
    ib = pi[k-4]; jb = pj[k-4];
  }
  const int i0 = ib*64, j0 = jb*64;
  float* A = out + (size_t)b*65536;
  const int tid = threadIdx.x;
  const int r = tid >> 2, c0 = (tid & 3) * 16;
#pragma unroll
  for (int q = 0; q < 4; ++q) {
    const float4 v = *(const float4*)(A + (i0 + r)*256 + j0 + c0 + q*4);
    tile[r][c0+q*4+0] = v.x;
    tile[r][c0+q*4+1] = v.y;
    tile[r][c0+q*4+2] = v.z;
    tile[r][c0+q*4+3] = v.w;
  }
  __syncthreads();
  if (ib != jb) {
#pragma unroll
    for (int q = 0; q < 4; ++q) {
      const int c = c0 + q*4;
      float4 v;
      v.x = -tile[c+0][r]; v.y = -tile[c+1][r];
      v.z = -tile[c+2][r]; v.w = -tile[c+3][r];
      *(float4*)(A + (j0 + r)*256 + i0 + c) = v;
    }
  } else {
#pragma unroll
    for (int q = 0; q < 4; ++q) {
      const int cb = c0 + q*4;
      float4 v;
#pragma unroll
      for (int e = 0; e < 4; ++e) {
        const int c = cb + e;
        float val = (c < r) ? tile[r][c] : ((c == r) ? 0.f : -tile[c][r]);
        ((float*)&v)[e] = val;
      }
      *(float4*)(A + (i0 + r)*256 + j0 + cb) = v;
    }
  }
}

// ---------------------------------------------------------------------------
extern "C" void kernel_launch(void* const* d_in, const int* in_sizes, int n_in,
                              void* d_out, int out_size, void* d_ws, size_t ws_size,
                              hipStream_t stream) {
  const float* x  = (const float*)d_in[0];
  const float* W1 = (const float*)d_in[1];
  const float* b1 = (const float*)d_in[2];
  const float* W2 = (const float*)d_in[3];
  const float* b2 = (const float*)d_in[4];
  float* out = (float*)d_out;
  u16* h = (u16*)d_ws;                               // 2 MB (only ws use now)

  k1_gemm_softplus<<<dim3(64),        dim3(256), 0, stream>>>(x, W1, b1, h);
  k2_gemm_f32b    <<<dim3(2040),      dim3(256), 0, stream>>>(h, W2, b2, out);
  k3_mirror       <<<dim3(10, 1024),  dim3(256), 0, stream>>>(out);
}